// Round 2
// baseline (53.677 us; speedup 1.0000x reference)
//
#include <hip/hip_runtime.h>
#include <hip/hip_bf16.h>

// Problem constants: B=16384, N=20, D=64, R=3, K=64
#define BB   16384
#define NN   20
#define NREL 3

typedef __attribute__((ext_vector_type(8))) short  short8;
typedef __attribute__((ext_vector_type(4))) float  f32x4;

__device__ __forceinline__ float b2f(unsigned short v) {
    union { unsigned int u; float f; } x;
    x.u = ((unsigned int)v) << 16;
    return x.f;
}

// f32 -> bf16 (RNE), returned as raw ushort
__device__ __forceinline__ unsigned short f2bu(float f) {
    union { float f; unsigned int u; } x;
    x.f = f;
    unsigned int r = x.u + 0x7FFFu + ((x.u >> 16) & 1u);
    return (unsigned short)(r >> 16);
}

// ---------------------------------------------------------------------------
// K1: McatT[r*128+e][d] = sum_k w_uir[r][d][k] * w_aor[r][e][k]   (bf16 out)
//     cvec[r*128+e]     = sum_k r_vec[r][k]   * w_aor[r][e][k]    (f32 out)
// ---------------------------------------------------------------------------
__global__ __launch_bounds__(256) void k_precompute(
    const float* __restrict__ w_uir,
    const float* __restrict__ w_aor,
    const float* __restrict__ r_vec,
    unsigned short* __restrict__ McatT,   // [384][128] bf16 bits
    float* __restrict__ cvec)             // [384]
{
    int idx = blockIdx.x * 256 + threadIdx.x;
    if (idx < NREL * 128 * 128) {
        int d = idx & 127;
        int e = (idx >> 7) & 127;
        int r = idx >> 14;
        const float4* pu = reinterpret_cast<const float4*>(w_uir + (r * 128 + d) * 64);
        const float4* pa = reinterpret_cast<const float4*>(w_aor + (r * 128 + e) * 64);
        float acc = 0.f;
        #pragma unroll
        for (int k = 0; k < 16; ++k) {
            float4 a = pu[k], b = pa[k];
            acc += a.x * b.x + a.y * b.y + a.z * b.z + a.w * b.w;
        }
        McatT[(r * 128 + e) * 128 + d] = f2bu(acc);
    } else if (idx < NREL * 128 * 128 + NREL * 128) {
        int j = idx - NREL * 128 * 128;
        int r = j >> 7, e = j & 127;
        const float4* pr = reinterpret_cast<const float4*>(r_vec + r * 64);
        const float4* pa = reinterpret_cast<const float4*>(w_aor + (r * 128 + e) * 64);
        float acc = 0.f;
        #pragma unroll
        for (int k = 0; k < 16; ++k) {
            float4 a = pr[k], b = pa[k];
            acc += a.x * b.x + a.y * b.y + a.z * b.z + a.w * b.w;
        }
        cvec[j] = acc;
    }
}

// ---------------------------------------------------------------------------
// K2: v'[b][j] = sum_d ui_in[b][d] * McatT[j][d] + cvec[j]
//     GEMM M=16384 N=384 K=128, bf16 MFMA 16x16x32, 64x64 block tiles.
//     A tile staged f32 -> bf16 in LDS. Output vp in bf16.
// ---------------------------------------------------------------------------
__global__ __launch_bounds__(256) void k_gemm(
    const float* __restrict__ u_emb,
    const float* __restrict__ i_emb,
    const unsigned short* __restrict__ McatT,  // [384][128] bf16 bits
    const float* __restrict__ cvec,            // [384]
    unsigned short* __restrict__ vp)           // [16384][384] bf16 bits
{
    __shared__ unsigned short Atile[64][136];  // +8 pad
    const int t = threadIdx.x;
    const int bm = blockIdx.x & 255;   // 256 M tiles
    const int bn = blockIdx.x >> 8;    // 6 N tiles
    const int Mbase = bm * 64;
    const int Nbase = bn * 64;

    // stage A tile [64 rows][128 cols = u|i concat], f32 load -> bf16 LDS
    #pragma unroll
    for (int it = 0; it < 8; ++it) {
        int idx  = it * 256 + t;       // 0..2047, each covers 4 floats
        int row  = idx >> 5;
        int colg = idx & 31;
        const float* src = (colg < 16)
            ? (u_emb + (Mbase + row) * 64 + colg * 4)
            : (i_emb + (Mbase + row) * 64 + (colg - 16) * 4);
        float4 v = *reinterpret_cast<const float4*>(src);
        ushort4 h;
        h.x = f2bu(v.x); h.y = f2bu(v.y); h.z = f2bu(v.z); h.w = f2bu(v.w);
        *reinterpret_cast<ushort4*>(&Atile[row][colg * 4]) = h;
    }
    __syncthreads();

    const int w    = t >> 6;
    const int lane = t & 63;
    const int lr   = lane & 15;
    const int lk   = (lane >> 4) * 8;

    short8 afrag[4];
    #pragma unroll
    for (int kk = 0; kk < 4; ++kk)
        afrag[kk] = *reinterpret_cast<const short8*>(&Atile[w * 16 + lr][kk * 32 + lk]);

    #pragma unroll
    for (int nt = 0; nt < 4; ++nt) {
        f32x4 acc = {0.f, 0.f, 0.f, 0.f};
        int col = Nbase + nt * 16 + lr;
        #pragma unroll
        for (int kk = 0; kk < 4; ++kk) {
            short8 bfrag = *reinterpret_cast<const short8*>(McatT + col * 128 + kk * 32 + lk);
            acc = __builtin_amdgcn_mfma_f32_16x16x32_bf16(afrag[kk], bfrag, acc, 0, 0, 0);
        }
        float cb = cvec[col];
        #pragma unroll
        for (int reg = 0; reg < 4; ++reg) {
            int grow = Mbase + w * 16 + (lane >> 4) * 4 + reg;
            vp[grow * 384 + col] = f2bu(acc[reg] + cb);
        }
    }
}

// ---------------------------------------------------------------------------
// K3: pred[t] = sum_e ao_in[t][e] * v'[b][s[t]*128 + e],  ao_in = [a|o]
//     16 lanes per triple; float4 a/o loads, ushort4 vp loads, shfl reduce.
// ---------------------------------------------------------------------------
__global__ __launch_bounds__(256) void k_pred(
    const float* __restrict__ a_emb,
    const float* __restrict__ o_emb,
    const int* __restrict__ s,
    const unsigned short* __restrict__ vp,
    float* __restrict__ out)
{
    int gt   = blockIdx.x * 256 + threadIdx.x;
    int trip = gt >> 4;            // 0..327679 (grid exact)
    int j    = gt & 15;
    int b    = trip / NN;

    float4 av = *reinterpret_cast<const float4*>(a_emb + trip * 64 + j * 4);
    float4 ov = *reinterpret_cast<const float4*>(o_emb + trip * 64 + j * 4);
    int sv = s[trip];
    const unsigned short* vb = vp + b * 384 + sv * 128;
    ushort4 v0 = *reinterpret_cast<const ushort4*>(vb + j * 4);
    ushort4 v1 = *reinterpret_cast<const ushort4*>(vb + 64 + j * 4);

    float sum = av.x * b2f(v0.x) + av.y * b2f(v0.y) + av.z * b2f(v0.z) + av.w * b2f(v0.w)
              + ov.x * b2f(v1.x) + ov.y * b2f(v1.y) + ov.z * b2f(v1.z) + ov.w * b2f(v1.w);
    sum += __shfl_xor(sum, 8, 64);
    sum += __shfl_xor(sum, 4, 64);
    sum += __shfl_xor(sum, 2, 64);
    sum += __shfl_xor(sum, 1, 64);
    if (j == 0)
        out[trip] = sum;
}

// ---------------------------------------------------------------------------
extern "C" void kernel_launch(void* const* d_in, const int* in_sizes, int n_in,
                              void* d_out, int out_size, void* d_ws, size_t ws_size,
                              hipStream_t stream) {
    const float* u_emb = (const float*)d_in[0];
    const float* i_emb = (const float*)d_in[1];
    const float* a_emb = (const float*)d_in[2];
    const float* o_emb = (const float*)d_in[3];
    const int*   s     = (const int*)d_in[4];
    const float* w_uir = (const float*)d_in[5];
    const float* w_aor = (const float*)d_in[6];
    const float* r_vec = (const float*)d_in[7];
    float* out = (float*)d_out;

    char* ws = (char*)d_ws;
    unsigned short* McatT = (unsigned short*)ws;              // 98304 B
    float*          cvec  = (float*)(ws + 98304);             // 1536 B
    unsigned short* vp    = (unsigned short*)(ws + 102400);   // 12.58 MB

    k_precompute<<<194, 256, 0, stream>>>(w_uir, w_aor, r_vec, McatT, cvec);
    k_gemm<<<1536, 256, 0, stream>>>(u_emb, i_emb, McatT, cvec, vp);
    k_pred<<<20480, 256, 0, stream>>>(a_emb, o_emb, s, vp, out);
}